// Round 1
// baseline (3387.922 us; speedup 1.0000x reference)
//
#include <hip/hip_runtime.h>
#include <stdint.h>
#include <math.h>

// Problem constants
#define DD 4096
#define LL 24
#define NP 576
#define TT 128
#define RED 1024
#define MTOT (LL * NP)   // 13824

#define NEG_INF (-3.402823466e+38f)

typedef __bf16 bf16x8 __attribute__((ext_vector_type(8)));
typedef float f32x4 __attribute__((ext_vector_type(4)));

// ---------------------------------------------------------------- helpers
__device__ inline unsigned short bf16_rn(float a) {
  unsigned u = __float_as_uint(a);
  return (unsigned short)((u + 0x7FFFu + ((u >> 16) & 1u)) >> 16);
}
__device__ inline void bsplit(float a, unsigned short& h, unsigned short& l) {
  unsigned short hb = bf16_rn(a);
  float hf = __uint_as_float(((unsigned)hb) << 16);
  h = hb;
  l = bf16_rn(a - hf);
}
__device__ inline float wave_sum(float v) {
  #pragma unroll
  for (int off = 32; off > 0; off >>= 1) v += __shfl_down(v, off);
  return v;
}
__device__ inline float sigm(float x) { return 1.0f / (1.0f + expf(-x)); }

// numpy float32 pairwise sum for n <= 128 (matches numpy's exact order)
__device__ inline float np_sum(const float* a, int n) {
  if (n < 8) {
    float r = 0.0f;
    for (int i = 0; i < n; ++i) r += a[i];
    return r;
  }
  float r0 = a[0], r1 = a[1], r2 = a[2], r3 = a[3];
  float r4 = a[4], r5 = a[5], r6 = a[6], r7 = a[7];
  int i = 8;
  for (; i + 8 <= n; i += 8) {
    r0 += a[i + 0]; r1 += a[i + 1]; r2 += a[i + 2]; r3 += a[i + 3];
    r4 += a[i + 4]; r5 += a[i + 5]; r6 += a[i + 6]; r7 += a[i + 7];
  }
  float res = ((r0 + r1) + (r2 + r3)) + ((r4 + r5) + (r6 + r7));
  for (; i < n; ++i) res += a[i];
  return res;
}

// ---------------------------------------------------------------- small prep kernels
// tmean[d] = mean over T of text_features[t][d]
__global__ __launch_bounds__(256) void k_text_mean(const float4* __restrict__ tf, float4* __restrict__ tmean) {
  int i = blockIdx.x * 256 + threadIdx.x;        // 0..1023 (D/4)
  float a = 0, b = 0, c = 0, d = 0;
  for (int t = 0; t < TT; ++t) {
    float4 v = tf[(size_t)t * (DD / 4) + i];
    a += v.x; b += v.y; c += v.z; d += v.w;
  }
  float4 o; o.x = a * (1.0f / TT); o.y = b * (1.0f / TT); o.z = c * (1.0f / TT); o.w = d * (1.0f / TT);
  tmean[i] = o;
}

// single-block LN (no affine), n = 4096, eps = 1e-5
__global__ __launch_bounds__(256) void k_ln_vec(const float* __restrict__ in, float* __restrict__ out) {
  __shared__ float red[256];
  int tid = threadIdx.x;
  float s = 0;
  for (int i = tid; i < DD; i += 256) s += in[i];
  red[tid] = s; __syncthreads();
  for (int o = 128; o > 0; o >>= 1) { if (tid < o) red[tid] += red[tid + o]; __syncthreads(); }
  float mu = red[0] / (float)DD;
  __syncthreads();
  float v = 0;
  for (int i = tid; i < DD; i += 256) { float d0 = in[i] - mu; v += d0 * d0; }
  red[tid] = v; __syncthreads();
  for (int o = 128; o > 0; o >>= 1) { if (tid < o) red[tid] += red[tid + o]; __syncthreads(); }
  float isd = 1.0f / sqrtf(red[0] / (float)DD + 1e-5f);
  for (int i = tid; i < DD; i += 256) out[i] = (in[i] - mu) * isd;
}

// y[l][d] = mean over N of proj[l][n][d]
__global__ __launch_bounds__(256) void k_y_mean(const float4* __restrict__ proj, float4* __restrict__ y) {
  int i4 = blockIdx.x * 256 + threadIdx.x;       // 0..24575
  int l = i4 >> 10;
  int d4 = i4 & 1023;
  const float4* base = proj + (size_t)l * NP * (DD / 4) + d4;
  float a = 0, b = 0, c = 0, d = 0;
  for (int n = 0; n < NP; ++n) {
    float4 v = base[(size_t)n * (DD / 4)];
    a += v.x; b += v.y; c += v.z; d += v.w;
  }
  float4 o; o.x = a * (1.0f / NP); o.y = b * (1.0f / NP); o.z = c * (1.0f / NP); o.w = d * (1.0f / NP);
  y[i4] = o;
}

// base1[l][r] = W1b[r,:]·y[l] + W1c[r,:]·tg + W1_b[r]   (batched over layers)
__global__ __launch_bounds__(256) void k_base1(const float* __restrict__ W1, const float* __restrict__ W1bias,
                                               const float* __restrict__ y, const float* __restrict__ tg,
                                               float* __restrict__ base1) {
  const int r = blockIdx.x;
  const int tid = threadIdx.x;
  const float* rowB = W1 + (size_t)r * (3 * DD) + DD;
  const float* rowC = W1 + (size_t)r * (3 * DD) + 2 * DD;
  float part[LL];
  #pragma unroll
  for (int l = 0; l < LL; ++l) part[l] = 0.0f;
  float ptg = 0.0f;
  for (int d = tid; d < DD; d += 256) {
    float wb = rowB[d], wc = rowC[d];
    ptg += wc * tg[d];
    #pragma unroll
    for (int l = 0; l < LL; ++l) part[l] += wb * y[l * DD + d];
  }
  __shared__ float red[4 * 25];
  int wv = tid >> 6, lane = tid & 63;
  #pragma unroll
  for (int l = 0; l < LL; ++l) {
    float v = wave_sum(part[l]);
    if (lane == 0) red[wv * 25 + l] = v;
  }
  {
    float v = wave_sum(ptg);
    if (lane == 0) red[wv * 25 + 24] = v;
  }
  __syncthreads();
  if (tid < LL) {
    float v = red[tid] + red[25 + tid] + red[50 + tid] + red[75 + tid];
    float t = red[24] + red[49] + red[74] + red[99];
    base1[tid * RED + r] = v + t + W1bias[r];
  }
}

__global__ __launch_bounds__(256) void k_init(float* __restrict__ c0, float* __restrict__ sg0) {
  int i = blockIdx.x * 256 + threadIdx.x;
  if (i < DD) { c0[i] = 0.0f; sg0[i] = 0.5f; }
}

// s[r] = relu(W1a[r,:]·sigc + base1l[r])
__global__ __launch_bounds__(256) void k_dsu_A(const float* __restrict__ W1, const float* __restrict__ sigc,
                                               const float* __restrict__ base1l, float* __restrict__ s_out) {
  const int r = blockIdx.x;
  const int tid = threadIdx.x;
  const float* row = W1 + (size_t)r * (3 * DD);
  float acc = 0.0f;
  for (int d = tid; d < DD; d += 256) acc += row[d] * sigc[d];
  acc = wave_sum(acc);
  __shared__ float red[4];
  if ((tid & 63) == 0) red[tid >> 6] = acc;
  __syncthreads();
  if (tid == 0) {
    float v = red[0] + red[1] + red[2] + red[3] + base1l[r];
    s_out[r] = fmaxf(v, 0.0f);
  }
}

// gate matvecs + combine: c_out[d], sigc_out[d]
__global__ __launch_bounds__(192) void k_dsu_B(const float* __restrict__ Wc, const float* __restrict__ Wi,
                                               const float* __restrict__ Wf, const float* __restrict__ Wcb,
                                               const float* __restrict__ Wib, const float* __restrict__ Wfb,
                                               const float* __restrict__ bcv, const float* __restrict__ biv,
                                               const float* __restrict__ bfv, const float* __restrict__ s,
                                               const float* __restrict__ c_in, float* __restrict__ c_out,
                                               float* __restrict__ sigc_out) {
  const int d = blockIdx.x;
  const int wv = threadIdx.x / 64, lane = threadIdx.x & 63;
  const float* W = (wv == 0) ? Wc : (wv == 1) ? Wi : Wf;
  const float* row = W + (size_t)d * RED;
  float acc = 0.0f;
  for (int r = lane; r < RED; r += 64) acc += row[r] * s[r];
  acc = wave_sum(acc);
  __shared__ float us[3];
  if (lane == 0) us[wv] = acc;
  __syncthreads();
  if (threadIdx.x == 0) {
    float ct = tanhf(us[0] + Wcb[d] + bcv[d]);
    float ig = sigm(us[1] + Wib[d] + biv[d]);
    float fg = sigm(us[2] + Wfb[d] + bfv[d]);
    float c = fg * c_in[d] + ig * ct;
    c_out[d] = c;
    sigc_out[d] = sigm(c);
  }
}

// u[e] = Wq[e,:]·c_final
__global__ __launch_bounds__(256) void k_qvec(const float* __restrict__ Wq, const float* __restrict__ c,
                                              float* __restrict__ u) {
  const int e = blockIdx.x;
  const int tid = threadIdx.x;
  const float* row = Wq + (size_t)e * DD;
  float acc = 0.0f;
  for (int d = tid; d < DD; d += 256) acc += row[d] * c[d];
  acc = wave_sum(acc);
  __shared__ float red[4];
  if ((tid & 63) == 0) red[tid >> 6] = acc;
  __syncthreads();
  if (tid == 0) u[e] = red[0] + red[1] + red[2] + red[3];
}

// q = LN(u)*ln_w + ln_b ; wtil = ln_w*q ; scal = {alpha=sum(wtil), beta=sum(ln_b*q)}
__global__ __launch_bounds__(256) void k_qln(const float* __restrict__ u, const float* __restrict__ lnw,
                                             const float* __restrict__ lnb, float* __restrict__ wtil,
                                             float* __restrict__ scal) {
  __shared__ float red[256];
  int tid = threadIdx.x;
  float s = 0;
  for (int i = tid; i < DD; i += 256) s += u[i];
  red[tid] = s; __syncthreads();
  for (int o = 128; o > 0; o >>= 1) { if (tid < o) red[tid] += red[tid + o]; __syncthreads(); }
  float mu = red[0] / (float)DD;
  __syncthreads();
  float v = 0;
  for (int i = tid; i < DD; i += 256) { float d0 = u[i] - mu; v += d0 * d0; }
  red[tid] = v; __syncthreads();
  for (int o = 128; o > 0; o >>= 1) { if (tid < o) red[tid] += red[tid + o]; __syncthreads(); }
  float isd = 1.0f / sqrtf(red[0] / (float)DD + 1e-5f);
  __syncthreads();
  float a = 0, b = 0;
  for (int i = tid; i < DD; i += 256) {
    float q = (u[i] - mu) * isd * lnw[i] + lnb[i];
    float wt = lnw[i] * q;
    wtil[i] = wt;
    a += wt;
    b += lnb[i] * q;
  }
  red[tid] = a; __syncthreads();
  for (int o = 128; o > 0; o >>= 1) { if (tid < o) red[tid] += red[tid + o]; __syncthreads(); }
  float alpha = red[0];
  __syncthreads();
  red[tid] = b; __syncthreads();
  for (int o = 128; o > 0; o >>= 1) { if (tid < o) red[tid] += red[tid + o]; __syncthreads(); }
  if (tid == 0) { scal[0] = alpha; scal[1] = red[0]; }
}

// fp32 -> (bf16 hi, bf16 lo) split, 4 elems/thread, exact grid
__global__ __launch_bounds__(256) void k_split(const float4* __restrict__ src, ushort4* __restrict__ hi,
                                               ushort4* __restrict__ lo) {
  size_t i = (size_t)blockIdx.x * 256 + threadIdx.x;
  float4 v = src[i];
  ushort4 h, l;
  bsplit(v.x, h.x, l.x);
  bsplit(v.y, h.y, l.y);
  bsplit(v.z, h.z, l.z);
  bsplit(v.w, h.w, l.w);
  hi[i] = h;
  lo[i] = l;
}

// ---------------------------------------------------------------- GEMM (split-bf16, fused row-stat epilogue)
#define GLDS16(g, l)                                                                     \
  __builtin_amdgcn_global_load_lds((__attribute__((address_space(1))) void*)(void*)(g),  \
                                   (__attribute__((address_space(3))) void*)(l), 16, 0, 0)

__global__ __launch_bounds__(256) void k_gemm(const unsigned short* __restrict__ Ahi,
                                              const unsigned short* __restrict__ Alo,
                                              const unsigned short* __restrict__ Bhi,
                                              const unsigned short* __restrict__ Blo,
                                              const float* __restrict__ wtilde,
                                              float* __restrict__ partials) {
  __shared__ __align__(16) unsigned short sAh[4096];
  __shared__ __align__(16) unsigned short sAl[4096];
  __shared__ __align__(16) unsigned short sBh[4096];
  __shared__ __align__(16) unsigned short sBl[4096];

  const int tid = threadIdx.x;
  const int w = tid >> 6, lane = tid & 63;
  const int m0 = blockIdx.x * 128, n0 = blockIdx.y * 128;

  // staging: flat byte layout [row][64B of k], wave w round r covers rows [16w+64r, +16)
  const int flat = w * 1024 + lane * 16;  // bytes (round 0)
  const int row0 = flat >> 6;
  const int colb = (flat & 63) >> 1;      // element offset within the 32-elem k slice

  const unsigned short* gA0h = Ahi + (size_t)(m0 + row0) * DD + colb;
  const unsigned short* gA1h = gA0h + (size_t)64 * DD;
  const unsigned short* gA0l = Alo + (size_t)(m0 + row0) * DD + colb;
  const unsigned short* gA1l = gA0l + (size_t)64 * DD;
  const unsigned short* gB0h = Bhi + (size_t)(n0 + row0) * DD + colb;
  const unsigned short* gB1h = gB0h + (size_t)64 * DD;
  const unsigned short* gB0l = Blo + (size_t)(n0 + row0) * DD + colb;
  const unsigned short* gB1l = gB0l + (size_t)64 * DD;

  const int r16 = lane & 15, qd = lane >> 4;
  const int wm = (w & 1) << 6, wn = (w >> 1) << 6;

  f32x4 acc[4][4];
  #pragma unroll
  for (int mi = 0; mi < 4; ++mi)
    #pragma unroll
    for (int ni = 0; ni < 4; ++ni) acc[mi][ni] = (f32x4){0.f, 0.f, 0.f, 0.f};

  for (int kk = 0; kk < DD / 32; ++kk) {
    __syncthreads();  // previous iteration's compute done before overwriting LDS
    GLDS16(gA0h, sAh + w * 512);
    GLDS16(gA1h, sAh + 2048 + w * 512);
    GLDS16(gA0l, sAl + w * 512);
    GLDS16(gA1l, sAl + 2048 + w * 512);
    GLDS16(gB0h, sBh + w * 512);
    GLDS16(gB1h, sBh + 2048 + w * 512);
    GLDS16(gB0l, sBl + w * 512);
    GLDS16(gB1l, sBl + 2048 + w * 512);
    gA0h += 32; gA1h += 32; gA0l += 32; gA1l += 32;
    gB0h += 32; gB1h += 32; gB0l += 32; gB1l += 32;
    __syncthreads();  // staging complete (vmcnt drained at barrier)

    bf16x8 ah[4], al[4], bh[4], bl[4];
    #pragma unroll
    for (int mi = 0; mi < 4; ++mi) {
      int off = (wm + mi * 16 + r16) * 32 + qd * 8;
      ah[mi] = *(const bf16x8*)(sAh + off);
      al[mi] = *(const bf16x8*)(sAl + off);
    }
    #pragma unroll
    for (int ni = 0; ni < 4; ++ni) {
      int off = (wn + ni * 16 + r16) * 32 + qd * 8;
      bh[ni] = *(const bf16x8*)(sBh + off);
      bl[ni] = *(const bf16x8*)(sBl + off);
    }
    #pragma unroll
    for (int mi = 0; mi < 4; ++mi)
      #pragma unroll
      for (int ni = 0; ni < 4; ++ni)
        acc[mi][ni] = __builtin_amdgcn_mfma_f32_16x16x32_bf16(ah[mi], bh[ni], acc[mi][ni], 0, 0, 0);
    #pragma unroll
    for (int mi = 0; mi < 4; ++mi)
      #pragma unroll
      for (int ni = 0; ni < 4; ++ni)
        acc[mi][ni] = __builtin_amdgcn_mfma_f32_16x16x32_bf16(ah[mi], bl[ni], acc[mi][ni], 0, 0, 0);
    #pragma unroll
    for (int mi = 0; mi < 4; ++mi)
      #pragma unroll
      for (int ni = 0; ni < 4; ++ni)
        acc[mi][ni] = __builtin_amdgcn_mfma_f32_16x16x32_bf16(al[mi], bh[ni], acc[mi][ni], 0, 0, 0);
  }

  // epilogue: per-row (v, v^2, v*wtilde) partial sums over this tile's 128 columns
  float wt[4];
  #pragma unroll
  for (int ni = 0; ni < 4; ++ni) wt[ni] = wtilde[n0 + wn + ni * 16 + r16];

  __syncthreads();
  float* epi = (float*)sAh;  // reuse LDS: 2 halves * 128 rows * 3 = 768 floats
  #pragma unroll
  for (int mi = 0; mi < 4; ++mi) {
    #pragma unroll
    for (int j = 0; j < 4; ++j) {
      float sv = 0, sv2 = 0, svw = 0;
      #pragma unroll
      for (int ni = 0; ni < 4; ++ni) {
        float v = acc[mi][ni][j];
        sv += v;
        sv2 += v * v;
        svw += v * wt[ni];
      }
      #pragma unroll
      for (int off = 1; off < 16; off <<= 1) {
        sv += __shfl_xor(sv, off);
        sv2 += __shfl_xor(sv2, off);
        svw += __shfl_xor(svw, off);
      }
      if (r16 == 0) {
        int row = wm + mi * 16 + qd * 4 + j;
        int half = w >> 1;
        epi[(half * 128 + row) * 3 + 0] = sv;
        epi[(half * 128 + row) * 3 + 1] = sv2;
        epi[(half * 128 + row) * 3 + 2] = svw;
      }
    }
  }
  __syncthreads();
  if (tid < 128) {
    size_t base = (size_t)(m0 + tid) * 96 + (size_t)blockIdx.y * 3;
    #pragma unroll
    for (int c = 0; c < 3; ++c) partials[base + c] = epi[tid * 3 + c] + epi[(128 + tid) * 3 + c];
  }
}

// scores[m] = isd*(svw - mu*alpha) + beta  (LN algebra folded)
__global__ __launch_bounds__(256) void k_scorefin(const float* __restrict__ partials,
                                                  const float* __restrict__ scal,
                                                  float* __restrict__ scores) {
  int m = blockIdx.x * 256 + threadIdx.x;  // 13824 exact
  const float* p = partials + (size_t)m * 96;
  float s1 = 0, s2 = 0, sw = 0;
  #pragma unroll
  for (int j = 0; j < 32; ++j) {
    s1 += p[j * 3 + 0];
    s2 += p[j * 3 + 1];
    sw += p[j * 3 + 2];
  }
  float mu = s1 * (1.0f / DD);
  float var = s2 * (1.0f / DD) - mu * mu;
  float isd = 1.0f / sqrtf(var + 1e-5f);
  scores[m] = isd * (sw - mu * scal[0]) + scal[1];
}

// per-layer z-score + conf
__global__ __launch_bounds__(256) void k_zscore(const float* __restrict__ scores, float* __restrict__ z,
                                                float* __restrict__ conf) {
  const int l = blockIdx.x;
  const int tid = threadIdx.x;
  const float* s = scores + l * NP;
  __shared__ float red[256];
  float a = 0;
  for (int i = tid; i < NP; i += 256) a += s[i];
  red[tid] = a; __syncthreads();
  for (int o = 128; o > 0; o >>= 1) { if (tid < o) red[tid] += red[tid + o]; __syncthreads(); }
  float mu = red[0] / (float)NP;
  __syncthreads();
  float v = 0;
  for (int i = tid; i < NP; i += 256) { float d0 = s[i] - mu; v += d0 * d0; }
  red[tid] = v; __syncthreads();
  for (int o = 128; o > 0; o >>= 1) { if (tid < o) red[tid] += red[tid + o]; __syncthreads(); }
  float sd = sqrtf(red[0] / (float)NP);
  float inv = 1.0f / (sd + 1e-6f);
  __syncthreads();
  float mx = NEG_INF;
  for (int i = tid; i < NP; i += 256) {
    float zz = (s[i] - mu) * inv;
    z[l * NP + i] = zz;
    mx = fmaxf(mx, zz);
  }
  red[tid] = mx; __syncthreads();
  for (int o = 128; o > 0; o >>= 1) { if (tid < o) red[tid] = fmaxf(red[tid], red[tid + o]); __syncthreads(); }
  if (tid == 0) conf[l] = red[0];
}

// full _select replication, 1 block / 1 wave
__global__ __launch_bounds__(64) void k_select(const float* __restrict__ z, const float* __restrict__ conf,
                                               int* __restrict__ sel_li, int* __restrict__ sel_idx) {
  const int lane = threadIdx.x;
  __shared__ int kper[24];
  __shared__ int offs[25];
  __shared__ float zb[576];
  __shared__ float csc[160];
  __shared__ int cli[160];
  __shared__ int cidx[160];
  __shared__ int taken[160];
  __shared__ int selpos[64];

  if (lane == 0) {
    const int focus = 22;
    float cf[24];
    for (int l = 0; l < 24; ++l) cf[l] = conf[l];
    int other[24]; int no = 0;
    for (int l = 0; l < 24; ++l)
      if (l != focus && cf[l] > 2.0f) other[no++] = l;
    int kp[24];
    for (int l = 0; l < 24; ++l) kp[l] = 0;
    kp[focus] = 64;            // focus_cand = min(TOPK/2, N) = 64
    const int rest = 64;       // TOPK - focus_cand
    if (no > 0) {
      float wv[24];
      float cmax = cf[other[0]];
      for (int j = 1; j < no; ++j) cmax = fmaxf(cmax, cf[other[j]]);
      for (int j = 0; j < no; ++j) wv[j] = (float)exp((double)(cf[other[j]] - cmax));
      float wsum = np_sum(wv, no);
      for (int j = 0; j < no; ++j) wv[j] = wv[j] / wsum;
      int alloc[24]; int asum = 0;
      for (int j = 0; j < no; ++j) { alloc[j] = (int)floorf(wv[j] * 64.0f); asum += alloc[j]; }
      int rem = rest - asum;
      int used[24];
      for (int j = 0; j < no; ++j) used[j] = 0;
      for (int t = 0; t < no && rem > 0; ++t) {
        int bj = -1; float bw = -1e38f;
        for (int j = 0; j < no; ++j)
          if (!used[j] && wv[j] > bw) { bw = wv[j]; bj = j; }
        used[bj] = 1; alloc[bj] += 1; rem -= 1;
      }
      for (int j = 0; j < no; ++j)
        if (alloc[j] > 0) kp[other[j]] = (alloc[j] < NP) ? alloc[j] : NP;
    }
    int o = 0;
    for (int l = 0; l < 24; ++l) { kper[l] = kp[l]; offs[l] = o; o += kp[l]; }
    offs[24] = o;
  }
  __syncthreads();

  // per-layer top-k (sorted desc) into flat candidate list (layer-ascending)
  for (int l = 0; l < 24; ++l) {
    const int kl = kper[l];
    if (kl == 0) continue;
    for (int i = lane; i < NP; i += 64) zb[i] = z[l * NP + i];
    __syncthreads();
    const int base = offs[l];
    for (int t = 0; t < kl; ++t) {
      float bv = NEG_INF; int bi_ = 0x7fffffff;
      for (int i = lane; i < NP; i += 64) {
        float v = zb[i];
        if (v > bv) { bv = v; bi_ = i; }
      }
      #pragma unroll
      for (int off = 32; off > 0; off >>= 1) {
        float ov = __shfl_down(bv, off);
        int oi = __shfl_down(bi_, off);
        if (ov > bv || (ov == bv && oi < bi_)) { bv = ov; bi_ = oi; }
      }
      bv = __shfl(bv, 0);
      bi_ = __shfl(bi_, 0);
      if (lane == 0) {
        csc[base + t] = bv; cli[base + t] = l; cidx[base + t] = bi_;
        zb[bi_] = NEG_INF;
      }
      __syncthreads();
    }
    __syncthreads();
  }

  const int M = offs[24];
  const int foff = offs[22];
  for (int i = lane; i < M; i += 64) taken[i] = 0;
  __syncthreads();
  // part 1: top 32 focus candidates (already sorted desc)
  if (lane < 32) { selpos[lane] = foff + lane; taken[foff + lane] = 1; }
  __syncthreads();
  // part 2: top 32 of remaining pool by score desc
  for (int t = 0; t < 32; ++t) {
    float bv = NEG_INF; int bp = 0x7fffffff;
    for (int i = lane; i < M; i += 64) {
      if (!taken[i]) {
        float v = csc[i];
        if (v > bv || (v == bv && i < bp)) { bv = v; bp = i; }
      }
    }
    #pragma unroll
    for (int off = 32; off > 0; off >>= 1) {
      float ov = __shfl_down(bv, off);
      int op = __shfl_down(bp, off);
      if (ov > bv || (ov == bv && op < bp)) { bv = ov; bp = op; }
    }
    bp = __shfl(bp, 0);
    if (lane == 0) { selpos[32 + t] = bp; taken[bp] = 1; }
    __syncthreads();
  }
  // merge the two desc-sorted halves => global desc order
  if (lane == 0) {
    int a = 0, b = 32;
    for (int k = 0; k < 64; ++k) {
      bool takeA;
      if (a >= 32) takeA = false;
      else if (b >= 64) takeA = true;
      else takeA = (csc[selpos[a]] >= csc[selpos[b]]);
      int p = takeA ? selpos[a++] : selpos[b++];
      sel_li[k] = cli[p];
      sel_idx[k] = cidx[p];
    }
  }
}

__global__ __launch_bounds__(256) void k_gather(const float4* __restrict__ proj, const int* __restrict__ sel_li,
                                                const int* __restrict__ sel_idx, float4* __restrict__ out) {
  int r = blockIdx.x;
  int li = sel_li[r], idx = sel_idx[r];
  const float4* src = proj + (size_t)(li * NP + idx) * (DD / 4);
  float4* dst = out + (size_t)r * (DD / 4);
  for (int i = threadIdx.x; i < DD / 4; i += 256) dst[i] = src[i];
}

// ---------------------------------------------------------------- workspace layout (bytes, 256-aligned)
constexpr size_t OFF_AHI = 0;
constexpr size_t OFF_ALO = OFF_AHI + 113246208ull;   // 13824*4096*2
constexpr size_t OFF_BHI = OFF_ALO + 113246208ull;
constexpr size_t OFF_BLO = OFF_BHI + 33554432ull;    // 4096*4096*2
constexpr size_t OFF_PART = OFF_BLO + 33554432ull;   // 13824*32*3*4
constexpr size_t OFF_SCORE = OFF_PART + 5308416ull;
constexpr size_t OFF_Z = OFF_SCORE + 55296ull;
constexpr size_t OFF_TMEAN = OFF_Z + 55296ull;
constexpr size_t OFF_TG = OFF_TMEAN + 16384ull;
constexpr size_t OFF_Y = OFF_TG + 16384ull;
constexpr size_t OFF_BASE1 = OFF_Y + 393216ull;
constexpr size_t OFF_CA = OFF_BASE1 + 98304ull;
constexpr size_t OFF_CB = OFF_CA + 16384ull;
constexpr size_t OFF_SGA = OFF_CB + 16384ull;
constexpr size_t OFF_SGB = OFF_SGA + 16384ull;
constexpr size_t OFF_S = OFF_SGB + 16384ull;
constexpr size_t OFF_U = OFF_S + 4096ull;
constexpr size_t OFF_WT = OFF_U + 16384ull;
constexpr size_t OFF_SCAL = OFF_WT + 16384ull;
constexpr size_t OFF_CONF = OFF_SCAL + 256ull;
constexpr size_t OFF_SELLI = OFF_CONF + 256ull;
constexpr size_t OFF_SELIX = OFF_SELLI + 256ull;
// total ~ 299.7 MB required in d_ws

extern "C" void kernel_launch(void* const* d_in, const int* in_sizes, int n_in,
                              void* d_out, int out_size, void* d_ws, size_t ws_size,
                              hipStream_t stream) {
  (void)in_sizes; (void)n_in; (void)out_size; (void)ws_size;
  const float* tf = (const float*)d_in[0];
  const float* proj = (const float*)d_in[1];
  const float* Wq = (const float*)d_in[2];
  const float* Wk = (const float*)d_in[3];
  const float* ln_w = (const float*)d_in[4];
  const float* ln_b = (const float*)d_in[5];
  const float* W1w = (const float*)d_in[6];
  const float* W1b = (const float*)d_in[7];
  const float* Wcw = (const float*)d_in[8];
  const float* Wcb = (const float*)d_in[9];
  const float* Wiw = (const float*)d_in[10];
  const float* Wib = (const float*)d_in[11];
  const float* Wfw = (const float*)d_in[12];
  const float* Wfb = (const float*)d_in[13];
  const float* bc = (const float*)d_in[14];
  const float* bi = (const float*)d_in[15];
  const float* bf = (const float*)d_in[16];

  char* ws = (char*)d_ws;
  unsigned short* Ahi = (unsigned short*)(ws + OFF_AHI);
  unsigned short* Alo = (unsigned short*)(ws + OFF_ALO);
  unsigned short* Bhi = (unsigned short*)(ws + OFF_BHI);
  unsigned short* Blo = (unsigned short*)(ws + OFF_BLO);
  float* partials = (float*)(ws + OFF_PART);
  float* scores = (float*)(ws + OFF_SCORE);
  float* zbuf = (float*)(ws + OFF_Z);
  float* tmean = (float*)(ws + OFF_TMEAN);
  float* tg = (float*)(ws + OFF_TG);
  float* ybuf = (float*)(ws + OFF_Y);
  float* base1 = (float*)(ws + OFF_BASE1);
  float* cA = (float*)(ws + OFF_CA);
  float* cB = (float*)(ws + OFF_CB);
  float* sgA = (float*)(ws + OFF_SGA);
  float* sgB = (float*)(ws + OFF_SGB);
  float* svec = (float*)(ws + OFF_S);
  float* uvec = (float*)(ws + OFF_U);
  float* wtil = (float*)(ws + OFF_WT);
  float* scal = (float*)(ws + OFF_SCAL);
  float* conf = (float*)(ws + OFF_CONF);
  int* sel_li = (int*)(ws + OFF_SELLI);
  int* sel_idx = (int*)(ws + OFF_SELIX);

  // prep: means + text_global LN
  k_text_mean<<<4, 256, 0, stream>>>((const float4*)tf, (float4*)tmean);
  k_ln_vec<<<1, 256, 0, stream>>>(tmean, tg);
  k_y_mean<<<96, 256, 0, stream>>>((const float4*)proj, (float4*)ybuf);
  k_base1<<<1024, 256, 0, stream>>>(W1w, W1b, ybuf, tg, base1);
  k_init<<<16, 256, 0, stream>>>(cA, sgA);

  // DSU recurrence (only need contexts[22] => 23 iterations)
  float* cbuf[2] = {cA, cB};
  float* sgbuf[2] = {sgA, sgB};
  for (int l = 0; l < 23; ++l) {
    int pi = l & 1;
    k_dsu_A<<<1024, 256, 0, stream>>>(W1w, sgbuf[pi], base1 + (size_t)l * RED, svec);
    k_dsu_B<<<4096, 192, 0, stream>>>(Wcw, Wiw, Wfw, Wcb, Wib, Wfb, bc, bi, bf,
                                      svec, cbuf[pi], cbuf[1 - pi], sgbuf[1 - pi]);
  }
  // c_final = cbuf[1] (after l=22)
  k_qvec<<<4096, 256, 0, stream>>>(Wq, cbuf[1], uvec);
  k_qln<<<1, 256, 0, stream>>>(uvec, ln_w, ln_b, wtil, scal);

  // split-bf16 conversions
  k_split<<<55296, 256, 0, stream>>>((const float4*)proj, (ushort4*)Ahi, (ushort4*)Alo);
  k_split<<<16384, 256, 0, stream>>>((const float4*)Wk, (ushort4*)Bhi, (ushort4*)Blo);

  // main GEMM with fused per-row stats
  k_gemm<<<dim3(108, 32), 256, 0, stream>>>(Ahi, Alo, Bhi, Blo, wtil, partials);

  // scores -> z -> select -> gather
  k_scorefin<<<54, 256, 0, stream>>>(partials, scal, scores);
  k_zscore<<<24, 256, 0, stream>>>(scores, zbuf, conf);
  k_select<<<1, 64, 0, stream>>>(zbuf, conf, sel_li, sel_idx);
  k_gather<<<64, 256, 0, stream>>>((const float4*)proj, sel_li, sel_idx, (float4*)d_out);
}

// Round 2
// 2443.471 us; speedup vs baseline: 1.3865x; 1.3865x over previous
//
#include <hip/hip_runtime.h>
#include <stdint.h>
#include <math.h>

// Problem constants
#define DD 4096
#define LL 24
#define NP 576
#define TT 128
#define RED 1024
#define MTOT (LL * NP)   // 13824

#define NEG_INF (-3.402823466e+38f)

typedef __bf16 bf16x8 __attribute__((ext_vector_type(8)));
typedef float f32x4 __attribute__((ext_vector_type(4)));

// ---------------------------------------------------------------- helpers
__device__ inline unsigned short bf16_rn(float a) {
  unsigned u = __float_as_uint(a);
  return (unsigned short)((u + 0x7FFFu + ((u >> 16) & 1u)) >> 16);
}
__device__ inline void bsplit(float a, unsigned short& h, unsigned short& l) {
  unsigned short hb = bf16_rn(a);
  float hf = __uint_as_float(((unsigned)hb) << 16);
  h = hb;
  l = bf16_rn(a - hf);
}
__device__ inline float wave_sum(float v) {
  #pragma unroll
  for (int off = 32; off > 0; off >>= 1) v += __shfl_down(v, off);
  return v;
}
__device__ inline float sigm(float x) { return 1.0f / (1.0f + expf(-x)); }

// numpy float32 pairwise sum for n <= 128 (matches numpy's exact order)
__device__ inline float np_sum(const float* a, int n) {
  if (n < 8) {
    float r = 0.0f;
    for (int i = 0; i < n; ++i) r += a[i];
    return r;
  }
  float r0 = a[0], r1 = a[1], r2 = a[2], r3 = a[3];
  float r4 = a[4], r5 = a[5], r6 = a[6], r7 = a[7];
  int i = 8;
  for (; i + 8 <= n; i += 8) {
    r0 += a[i + 0]; r1 += a[i + 1]; r2 += a[i + 2]; r3 += a[i + 3];
    r4 += a[i + 4]; r5 += a[i + 5]; r6 += a[i + 6]; r7 += a[i + 7];
  }
  float res = ((r0 + r1) + (r2 + r3)) + ((r4 + r5) + (r6 + r7));
  for (; i < n; ++i) res += a[i];
  return res;
}

// ---------------------------------------------------------------- small prep kernels
// tmean[d] = mean over T of text_features[t][d]
__global__ __launch_bounds__(256) void k_text_mean(const float4* __restrict__ tf, float4* __restrict__ tmean) {
  int i = blockIdx.x * 256 + threadIdx.x;        // 0..1023 (D/4)
  float a = 0, b = 0, c = 0, d = 0;
  for (int t = 0; t < TT; ++t) {
    float4 v = tf[(size_t)t * (DD / 4) + i];
    a += v.x; b += v.y; c += v.z; d += v.w;
  }
  float4 o; o.x = a * (1.0f / TT); o.y = b * (1.0f / TT); o.z = c * (1.0f / TT); o.w = d * (1.0f / TT);
  tmean[i] = o;
}

// single-block LN (no affine), n = 4096, eps = 1e-5
__global__ __launch_bounds__(256) void k_ln_vec(const float* __restrict__ in, float* __restrict__ out) {
  __shared__ float red[256];
  int tid = threadIdx.x;
  float s = 0;
  for (int i = tid; i < DD; i += 256) s += in[i];
  red[tid] = s; __syncthreads();
  for (int o = 128; o > 0; o >>= 1) { if (tid < o) red[tid] += red[tid + o]; __syncthreads(); }
  float mu = red[0] / (float)DD;
  __syncthreads();
  float v = 0;
  for (int i = tid; i < DD; i += 256) { float d0 = in[i] - mu; v += d0 * d0; }
  red[tid] = v; __syncthreads();
  for (int o = 128; o > 0; o >>= 1) { if (tid < o) red[tid] += red[tid + o]; __syncthreads(); }
  float isd = 1.0f / sqrtf(red[0] / (float)DD + 1e-5f);
  for (int i = tid; i < DD; i += 256) out[i] = (in[i] - mu) * isd;
}

// y[l][d] = mean over N of proj[l][n][d]
__global__ __launch_bounds__(256) void k_y_mean(const float4* __restrict__ proj, float4* __restrict__ y) {
  int i4 = blockIdx.x * 256 + threadIdx.x;       // 0..24575
  int l = i4 >> 10;
  int d4 = i4 & 1023;
  const float4* base = proj + (size_t)l * NP * (DD / 4) + d4;
  float a = 0, b = 0, c = 0, d = 0;
  for (int n = 0; n < NP; ++n) {
    float4 v = base[(size_t)n * (DD / 4)];
    a += v.x; b += v.y; c += v.z; d += v.w;
  }
  float4 o; o.x = a * (1.0f / NP); o.y = b * (1.0f / NP); o.z = c * (1.0f / NP); o.w = d * (1.0f / NP);
  y[i4] = o;
}

// base1[l][r] = W1b[r,:]·y[l] + W1c[r,:]·tg + W1_b[r]   (batched over layers)
__global__ __launch_bounds__(256) void k_base1(const float* __restrict__ W1, const float* __restrict__ W1bias,
                                               const float* __restrict__ y, const float* __restrict__ tg,
                                               float* __restrict__ base1) {
  const int r = blockIdx.x;
  const int tid = threadIdx.x;
  const float* rowB = W1 + (size_t)r * (3 * DD) + DD;
  const float* rowC = W1 + (size_t)r * (3 * DD) + 2 * DD;
  float part[LL];
  #pragma unroll
  for (int l = 0; l < LL; ++l) part[l] = 0.0f;
  float ptg = 0.0f;
  for (int d = tid; d < DD; d += 256) {
    float wb = rowB[d], wc = rowC[d];
    ptg += wc * tg[d];
    #pragma unroll
    for (int l = 0; l < LL; ++l) part[l] += wb * y[l * DD + d];
  }
  __shared__ float red[4 * 25];
  int wv = tid >> 6, lane = tid & 63;
  #pragma unroll
  for (int l = 0; l < LL; ++l) {
    float v = wave_sum(part[l]);
    if (lane == 0) red[wv * 25 + l] = v;
  }
  {
    float v = wave_sum(ptg);
    if (lane == 0) red[wv * 25 + 24] = v;
  }
  __syncthreads();
  if (tid < LL) {
    float v = red[tid] + red[25 + tid] + red[50 + tid] + red[75 + tid];
    float t = red[24] + red[49] + red[74] + red[99];
    base1[tid * RED + r] = v + t + W1bias[r];
  }
}

__global__ __launch_bounds__(256) void k_init(float* __restrict__ c0, float* __restrict__ sg0) {
  int i = blockIdx.x * 256 + threadIdx.x;
  if (i < DD) { c0[i] = 0.0f; sg0[i] = 0.5f; }
}

// s[r] = relu(W1a[r,:]·sigc + base1l[r])   (float4-vectorized)
__global__ __launch_bounds__(256) void k_dsu_A(const float4* __restrict__ W1, const float4* __restrict__ sigc,
                                               const float* __restrict__ base1l, float* __restrict__ s_out) {
  const int r = blockIdx.x;
  const int tid = threadIdx.x;
  const float4* row = W1 + (size_t)r * (3 * DD / 4);
  float acc = 0.0f;
  #pragma unroll
  for (int i = tid; i < DD / 4; i += 256) {
    float4 w = row[i], x = sigc[i];
    acc += w.x * x.x + w.y * x.y + w.z * x.z + w.w * x.w;
  }
  acc = wave_sum(acc);
  __shared__ float red[4];
  if ((tid & 63) == 0) red[tid >> 6] = acc;
  __syncthreads();
  if (tid == 0) {
    float v = red[0] + red[1] + red[2] + red[3] + base1l[r];
    s_out[r] = fmaxf(v, 0.0f);
  }
}

// gate matvecs + combine: c_out[d], sigc_out[d]   (float4-vectorized)
__global__ __launch_bounds__(192) void k_dsu_B(const float4* __restrict__ Wc, const float4* __restrict__ Wi,
                                               const float4* __restrict__ Wf, const float* __restrict__ Wcb,
                                               const float* __restrict__ Wib, const float* __restrict__ Wfb,
                                               const float* __restrict__ bcv, const float* __restrict__ biv,
                                               const float* __restrict__ bfv, const float4* __restrict__ s,
                                               const float* __restrict__ c_in, float* __restrict__ c_out,
                                               float* __restrict__ sigc_out) {
  const int d = blockIdx.x;
  const int wv = threadIdx.x / 64, lane = threadIdx.x & 63;
  const float4* W = (wv == 0) ? Wc : (wv == 1) ? Wi : Wf;
  const float4* row = W + (size_t)d * (RED / 4);
  float acc = 0.0f;
  #pragma unroll
  for (int i = lane; i < RED / 4; i += 64) {
    float4 w = row[i], x = s[i];
    acc += w.x * x.x + w.y * x.y + w.z * x.z + w.w * x.w;
  }
  acc = wave_sum(acc);
  __shared__ float us[3];
  if (lane == 0) us[wv] = acc;
  __syncthreads();
  if (threadIdx.x == 0) {
    float ct = tanhf(us[0] + Wcb[d] + bcv[d]);
    float ig = sigm(us[1] + Wib[d] + biv[d]);
    float fg = sigm(us[2] + Wfb[d] + bfv[d]);
    float c = fg * c_in[d] + ig * ct;
    c_out[d] = c;
    sigc_out[d] = sigm(c);
  }
}

// u[e] = Wq[e,:]·c_final   (float4-vectorized)
__global__ __launch_bounds__(256) void k_qvec(const float4* __restrict__ Wq, const float4* __restrict__ c,
                                              float* __restrict__ u) {
  const int e = blockIdx.x;
  const int tid = threadIdx.x;
  const float4* row = Wq + (size_t)e * (DD / 4);
  float acc = 0.0f;
  #pragma unroll
  for (int i = tid; i < DD / 4; i += 256) {
    float4 w = row[i], x = c[i];
    acc += w.x * x.x + w.y * x.y + w.z * x.z + w.w * x.w;
  }
  acc = wave_sum(acc);
  __shared__ float red[4];
  if ((tid & 63) == 0) red[tid >> 6] = acc;
  __syncthreads();
  if (tid == 0) u[e] = red[0] + red[1] + red[2] + red[3];
}

// q = LN(u)*ln_w + ln_b ; wtil = ln_w*q ; scal = {alpha=sum(wtil), beta=sum(ln_b*q)}
__global__ __launch_bounds__(256) void k_qln(const float* __restrict__ u, const float* __restrict__ lnw,
                                             const float* __restrict__ lnb, float* __restrict__ wtil,
                                             float* __restrict__ scal) {
  __shared__ float red[256];
  int tid = threadIdx.x;
  float s = 0;
  for (int i = tid; i < DD; i += 256) s += u[i];
  red[tid] = s; __syncthreads();
  for (int o = 128; o > 0; o >>= 1) { if (tid < o) red[tid] += red[tid + o]; __syncthreads(); }
  float mu = red[0] / (float)DD;
  __syncthreads();
  float v = 0;
  for (int i = tid; i < DD; i += 256) { float d0 = u[i] - mu; v += d0 * d0; }
  red[tid] = v; __syncthreads();
  for (int o = 128; o > 0; o >>= 1) { if (tid < o) red[tid] += red[tid + o]; __syncthreads(); }
  float isd = 1.0f / sqrtf(red[0] / (float)DD + 1e-5f);
  __syncthreads();
  float a = 0, b = 0;
  for (int i = tid; i < DD; i += 256) {
    float q = (u[i] - mu) * isd * lnw[i] + lnb[i];
    float wt = lnw[i] * q;
    wtil[i] = wt;
    a += wt;
    b += lnb[i] * q;
  }
  red[tid] = a; __syncthreads();
  for (int o = 128; o > 0; o >>= 1) { if (tid < o) red[tid] += red[tid + o]; __syncthreads(); }
  float alpha = red[0];
  __syncthreads();
  red[tid] = b; __syncthreads();
  for (int o = 128; o > 0; o >>= 1) { if (tid < o) red[tid] += red[tid + o]; __syncthreads(); }
  if (tid == 0) { scal[0] = alpha; scal[1] = red[0]; }
}

// fp32 -> (bf16 hi, bf16 lo) split, 4 elems/thread, exact grid
__global__ __launch_bounds__(256) void k_split(const float4* __restrict__ src, ushort4* __restrict__ hi,
                                               ushort4* __restrict__ lo) {
  size_t i = (size_t)blockIdx.x * 256 + threadIdx.x;
  float4 v = src[i];
  ushort4 h, l;
  bsplit(v.x, h.x, l.x);
  bsplit(v.y, h.y, l.y);
  bsplit(v.z, h.z, l.z);
  bsplit(v.w, h.w, l.w);
  hi[i] = h;
  lo[i] = l;
}

// ---------------------------------------------------------------- GEMM (split-bf16, fused row-stat epilogue)
// Grid: (32 n-tiles [fastest], 108 m-tiles) so co-resident blocks share A rows
// and B (67 MB hi+lo) stays L3-resident -> A streams from HBM exactly once.
#define GLDS16(g, l)                                                                     \
  __builtin_amdgcn_global_load_lds((__attribute__((address_space(1))) void*)(void*)(g),  \
                                   (__attribute__((address_space(3))) void*)(l), 16, 0, 0)

__global__ __launch_bounds__(256) void k_gemm(const unsigned short* __restrict__ Ahi,
                                              const unsigned short* __restrict__ Alo,
                                              const unsigned short* __restrict__ Bhi,
                                              const unsigned short* __restrict__ Blo,
                                              const float* __restrict__ wtilde,
                                              float* __restrict__ partials) {
  __shared__ __align__(16) unsigned short sAh[4096];
  __shared__ __align__(16) unsigned short sAl[4096];
  __shared__ __align__(16) unsigned short sBh[4096];
  __shared__ __align__(16) unsigned short sBl[4096];

  const int tid = threadIdx.x;
  const int w = tid >> 6, lane = tid & 63;
  const int n0 = blockIdx.x * 128, m0 = blockIdx.y * 128;  // n fastest-varying

  // staging: flat byte layout [row][64B of k], wave w round r covers rows [16w+64r, +16)
  const int flat = w * 1024 + lane * 16;  // bytes (round 0)
  const int row0 = flat >> 6;
  const int colb = (flat & 63) >> 1;      // element offset within the 32-elem k slice

  const unsigned short* gA0h = Ahi + (size_t)(m0 + row0) * DD + colb;
  const unsigned short* gA1h = gA0h + (size_t)64 * DD;
  const unsigned short* gA0l = Alo + (size_t)(m0 + row0) * DD + colb;
  const unsigned short* gA1l = gA0l + (size_t)64 * DD;
  const unsigned short* gB0h = Bhi + (size_t)(n0 + row0) * DD + colb;
  const unsigned short* gB1h = gB0h + (size_t)64 * DD;
  const unsigned short* gB0l = Blo + (size_t)(n0 + row0) * DD + colb;
  const unsigned short* gB1l = gB0l + (size_t)64 * DD;

  const int r16 = lane & 15, qd = lane >> 4;
  const int wm = (w & 1) << 6, wn = (w >> 1) << 6;

  f32x4 acc[4][4];
  #pragma unroll
  for (int mi = 0; mi < 4; ++mi)
    #pragma unroll
    for (int ni = 0; ni < 4; ++ni) acc[mi][ni] = (f32x4){0.f, 0.f, 0.f, 0.f};

  for (int kk = 0; kk < DD / 32; ++kk) {
    __syncthreads();  // previous iteration's compute done before overwriting LDS
    GLDS16(gA0h, sAh + w * 512);
    GLDS16(gA1h, sAh + 2048 + w * 512);
    GLDS16(gA0l, sAl + w * 512);
    GLDS16(gA1l, sAl + 2048 + w * 512);
    GLDS16(gB0h, sBh + w * 512);
    GLDS16(gB1h, sBh + 2048 + w * 512);
    GLDS16(gB0l, sBl + w * 512);
    GLDS16(gB1l, sBl + 2048 + w * 512);
    gA0h += 32; gA1h += 32; gA0l += 32; gA1l += 32;
    gB0h += 32; gB1h += 32; gB0l += 32; gB1l += 32;
    __syncthreads();  // staging complete (vmcnt drained at barrier)

    bf16x8 ah[4], al[4], bh[4], bl[4];
    #pragma unroll
    for (int mi = 0; mi < 4; ++mi) {
      int off = (wm + mi * 16 + r16) * 32 + qd * 8;
      ah[mi] = *(const bf16x8*)(sAh + off);
      al[mi] = *(const bf16x8*)(sAl + off);
    }
    #pragma unroll
    for (int ni = 0; ni < 4; ++ni) {
      int off = (wn + ni * 16 + r16) * 32 + qd * 8;
      bh[ni] = *(const bf16x8*)(sBh + off);
      bl[ni] = *(const bf16x8*)(sBl + off);
    }
    #pragma unroll
    for (int mi = 0; mi < 4; ++mi)
      #pragma unroll
      for (int ni = 0; ni < 4; ++ni)
        acc[mi][ni] = __builtin_amdgcn_mfma_f32_16x16x32_bf16(ah[mi], bh[ni], acc[mi][ni], 0, 0, 0);
    #pragma unroll
    for (int mi = 0; mi < 4; ++mi)
      #pragma unroll
      for (int ni = 0; ni < 4; ++ni)
        acc[mi][ni] = __builtin_amdgcn_mfma_f32_16x16x32_bf16(ah[mi], bl[ni], acc[mi][ni], 0, 0, 0);
    #pragma unroll
    for (int mi = 0; mi < 4; ++mi)
      #pragma unroll
      for (int ni = 0; ni < 4; ++ni)
        acc[mi][ni] = __builtin_amdgcn_mfma_f32_16x16x32_bf16(al[mi], bh[ni], acc[mi][ni], 0, 0, 0);
  }

  // epilogue: per-row (v, v^2, v*wtilde) partial sums over this tile's 128 columns
  float wt[4];
  #pragma unroll
  for (int ni = 0; ni < 4; ++ni) wt[ni] = wtilde[n0 + wn + ni * 16 + r16];

  __syncthreads();
  float* epi = (float*)sAh;  // reuse LDS: 2 halves * 128 rows * 3 = 768 floats
  #pragma unroll
  for (int mi = 0; mi < 4; ++mi) {
    #pragma unroll
    for (int j = 0; j < 4; ++j) {
      float sv = 0, sv2 = 0, svw = 0;
      #pragma unroll
      for (int ni = 0; ni < 4; ++ni) {
        float v = acc[mi][ni][j];
        sv += v;
        sv2 += v * v;
        svw += v * wt[ni];
      }
      #pragma unroll
      for (int off = 1; off < 16; off <<= 1) {
        sv += __shfl_xor(sv, off);
        sv2 += __shfl_xor(sv2, off);
        svw += __shfl_xor(svw, off);
      }
      if (r16 == 0) {
        int row = wm + mi * 16 + qd * 4 + j;
        int half = w >> 1;
        epi[(half * 128 + row) * 3 + 0] = sv;
        epi[(half * 128 + row) * 3 + 1] = sv2;
        epi[(half * 128 + row) * 3 + 2] = svw;
      }
    }
  }
  __syncthreads();
  if (tid < 128) {
    size_t base = (size_t)(m0 + tid) * 96 + (size_t)blockIdx.x * 3;
    #pragma unroll
    for (int c = 0; c < 3; ++c) partials[base + c] = epi[tid * 3 + c] + epi[(128 + tid) * 3 + c];
  }
}

// scores[m] = isd*(svw - mu*alpha) + beta  (LN algebra folded)
__global__ __launch_bounds__(256) void k_scorefin(const float* __restrict__ partials,
                                                  const float* __restrict__ scal,
                                                  float* __restrict__ scores) {
  int m = blockIdx.x * 256 + threadIdx.x;  // 13824 exact
  const float* p = partials + (size_t)m * 96;
  float s1 = 0, s2 = 0, sw = 0;
  #pragma unroll
  for (int j = 0; j < 32; ++j) {
    s1 += p[j * 3 + 0];
    s2 += p[j * 3 + 1];
    sw += p[j * 3 + 2];
  }
  float mu = s1 * (1.0f / DD);
  float var = s2 * (1.0f / DD) - mu * mu;
  float isd = 1.0f / sqrtf(var + 1e-5f);
  scores[m] = isd * (sw - mu * scal[0]) + scal[1];
}

// per-layer z-score + conf
__global__ __launch_bounds__(256) void k_zscore(const float* __restrict__ scores, float* __restrict__ z,
                                                float* __restrict__ conf) {
  const int l = blockIdx.x;
  const int tid = threadIdx.x;
  const float* s = scores + l * NP;
  __shared__ float red[256];
  float a = 0;
  for (int i = tid; i < NP; i += 256) a += s[i];
  red[tid] = a; __syncthreads();
  for (int o = 128; o > 0; o >>= 1) { if (tid < o) red[tid] += red[tid + o]; __syncthreads(); }
  float mu = red[0] / (float)NP;
  __syncthreads();
  float v = 0;
  for (int i = tid; i < NP; i += 256) { float d0 = s[i] - mu; v += d0 * d0; }
  red[tid] = v; __syncthreads();
  for (int o = 128; o > 0; o >>= 1) { if (tid < o) red[tid] += red[tid + o]; __syncthreads(); }
  float sd = sqrtf(red[0] / (float)NP);
  float inv = 1.0f / (sd + 1e-6f);
  __syncthreads();
  float mx = NEG_INF;
  for (int i = tid; i < NP; i += 256) {
    float zz = (s[i] - mu) * inv;
    z[l * NP + i] = zz;
    mx = fmaxf(mx, zz);
  }
  red[tid] = mx; __syncthreads();
  for (int o = 128; o > 0; o >>= 1) { if (tid < o) red[tid] = fmaxf(red[tid], red[tid + o]); __syncthreads(); }
  if (tid == 0) conf[l] = red[0];
}

// full _select replication, 1 block / 1 wave
__global__ __launch_bounds__(64) void k_select(const float* __restrict__ z, const float* __restrict__ conf,
                                               int* __restrict__ sel_li, int* __restrict__ sel_idx) {
  const int lane = threadIdx.x;
  __shared__ int kper[24];
  __shared__ int offs[25];
  __shared__ float zb[576];
  __shared__ float csc[160];
  __shared__ int cli[160];
  __shared__ int cidx[160];
  __shared__ int taken[160];
  __shared__ int selpos[64];

  if (lane == 0) {
    const int focus = 22;
    float cf[24];
    for (int l = 0; l < 24; ++l) cf[l] = conf[l];
    int other[24]; int no = 0;
    for (int l = 0; l < 24; ++l)
      if (l != focus && cf[l] > 2.0f) other[no++] = l;
    int kp[24];
    for (int l = 0; l < 24; ++l) kp[l] = 0;
    kp[focus] = 64;            // focus_cand = min(TOPK/2, N) = 64
    const int rest = 64;       // TOPK - focus_cand
    if (no > 0) {
      float wv[24];
      float cmax = cf[other[0]];
      for (int j = 1; j < no; ++j) cmax = fmaxf(cmax, cf[other[j]]);
      for (int j = 0; j < no; ++j) wv[j] = (float)exp((double)(cf[other[j]] - cmax));
      float wsum = np_sum(wv, no);
      for (int j = 0; j < no; ++j) wv[j] = wv[j] / wsum;
      int alloc[24]; int asum = 0;
      for (int j = 0; j < no; ++j) { alloc[j] = (int)floorf(wv[j] * 64.0f); asum += alloc[j]; }
      int rem = rest - asum;
      int used[24];
      for (int j = 0; j < no; ++j) used[j] = 0;
      for (int t = 0; t < no && rem > 0; ++t) {
        int bj = -1; float bw = -1e38f;
        for (int j = 0; j < no; ++j)
          if (!used[j] && wv[j] > bw) { bw = wv[j]; bj = j; }
        used[bj] = 1; alloc[bj] += 1; rem -= 1;
      }
      for (int j = 0; j < no; ++j)
        if (alloc[j] > 0) kp[other[j]] = (alloc[j] < NP) ? alloc[j] : NP;
    }
    int o = 0;
    for (int l = 0; l < 24; ++l) { kper[l] = kp[l]; offs[l] = o; o += kp[l]; }
    offs[24] = o;
  }
  __syncthreads();

  // per-layer top-k (sorted desc) into flat candidate list (layer-ascending)
  for (int l = 0; l < 24; ++l) {
    const int kl = kper[l];
    if (kl == 0) continue;
    for (int i = lane; i < NP; i += 64) zb[i] = z[l * NP + i];
    __syncthreads();
    const int base = offs[l];
    for (int t = 0; t < kl; ++t) {
      float bv = NEG_INF; int bi_ = 0x7fffffff;
      for (int i = lane; i < NP; i += 64) {
        float v = zb[i];
        if (v > bv) { bv = v; bi_ = i; }
      }
      #pragma unroll
      for (int off = 32; off > 0; off >>= 1) {
        float ov = __shfl_down(bv, off);
        int oi = __shfl_down(bi_, off);
        if (ov > bv || (ov == bv && oi < bi_)) { bv = ov; bi_ = oi; }
      }
      bv = __shfl(bv, 0);
      bi_ = __shfl(bi_, 0);
      if (lane == 0) {
        csc[base + t] = bv; cli[base + t] = l; cidx[base + t] = bi_;
        zb[bi_] = NEG_INF;
      }
      __syncthreads();
    }
    __syncthreads();
  }

  const int M = offs[24];
  const int foff = offs[22];
  for (int i = lane; i < M; i += 64) taken[i] = 0;
  __syncthreads();
  // part 1: top 32 focus candidates (already sorted desc)
  if (lane < 32) { selpos[lane] = foff + lane; taken[foff + lane] = 1; }
  __syncthreads();
  // part 2: top 32 of remaining pool by score desc
  for (int t = 0; t < 32; ++t) {
    float bv = NEG_INF; int bp = 0x7fffffff;
    for (int i = lane; i < M; i += 64) {
      if (!taken[i]) {
        float v = csc[i];
        if (v > bv || (v == bv && i < bp)) { bv = v; bp = i; }
      }
    }
    #pragma unroll
    for (int off = 32; off > 0; off >>= 1) {
      float ov = __shfl_down(bv, off);
      int op = __shfl_down(bp, off);
      if (ov > bv || (ov == bv && op < bp)) { bv = ov; bp = op; }
    }
    bp = __shfl(bp, 0);
    if (lane == 0) { selpos[32 + t] = bp; taken[bp] = 1; }
    __syncthreads();
  }
  // merge the two desc-sorted halves => global desc order
  if (lane == 0) {
    int a = 0, b = 32;
    for (int k = 0; k < 64; ++k) {
      bool takeA;
      if (a >= 32) takeA = false;
      else if (b >= 64) takeA = true;
      else takeA = (csc[selpos[a]] >= csc[selpos[b]]);
      int p = takeA ? selpos[a++] : selpos[b++];
      sel_li[k] = cli[p];
      sel_idx[k] = cidx[p];
    }
  }
}

__global__ __launch_bounds__(256) void k_gather(const float4* __restrict__ proj, const int* __restrict__ sel_li,
                                                const int* __restrict__ sel_idx, float4* __restrict__ out) {
  int r = blockIdx.x;
  int li = sel_li[r], idx = sel_idx[r];
  const float4* src = proj + (size_t)(li * NP + idx) * (DD / 4);
  float4* dst = out + (size_t)r * (DD / 4);
  for (int i = threadIdx.x; i < DD / 4; i += 256) dst[i] = src[i];
}

// ---------------------------------------------------------------- workspace layout (bytes, 256-aligned)
constexpr size_t OFF_AHI = 0;
constexpr size_t OFF_ALO = OFF_AHI + 113246208ull;   // 13824*4096*2
constexpr size_t OFF_BHI = OFF_ALO + 113246208ull;
constexpr size_t OFF_BLO = OFF_BHI + 33554432ull;    // 4096*4096*2
constexpr size_t OFF_PART = OFF_BLO + 33554432ull;   // 13824*32*3*4
constexpr size_t OFF_SCORE = OFF_PART + 5308416ull;
constexpr size_t OFF_Z = OFF_SCORE + 55296ull;
constexpr size_t OFF_TMEAN = OFF_Z + 55296ull;
constexpr size_t OFF_TG = OFF_TMEAN + 16384ull;
constexpr size_t OFF_Y = OFF_TG + 16384ull;
constexpr size_t OFF_BASE1 = OFF_Y + 393216ull;
constexpr size_t OFF_CA = OFF_BASE1 + 98304ull;
constexpr size_t OFF_CB = OFF_CA + 16384ull;
constexpr size_t OFF_SGA = OFF_CB + 16384ull;
constexpr size_t OFF_SGB = OFF_SGA + 16384ull;
constexpr size_t OFF_S = OFF_SGB + 16384ull;
constexpr size_t OFF_U = OFF_S + 4096ull;
constexpr size_t OFF_WT = OFF_U + 16384ull;
constexpr size_t OFF_SCAL = OFF_WT + 16384ull;
constexpr size_t OFF_CONF = OFF_SCAL + 256ull;
constexpr size_t OFF_SELLI = OFF_CONF + 256ull;
constexpr size_t OFF_SELIX = OFF_SELLI + 256ull;
// total ~ 299.7 MB required in d_ws

extern "C" void kernel_launch(void* const* d_in, const int* in_sizes, int n_in,
                              void* d_out, int out_size, void* d_ws, size_t ws_size,
                              hipStream_t stream) {
  (void)in_sizes; (void)n_in; (void)out_size; (void)ws_size;
  const float* tf = (const float*)d_in[0];
  const float* proj = (const float*)d_in[1];
  const float* Wq = (const float*)d_in[2];
  const float* Wk = (const float*)d_in[3];
  const float* ln_w = (const float*)d_in[4];
  const float* ln_b = (const float*)d_in[5];
  const float* W1w = (const float*)d_in[6];
  const float* W1b = (const float*)d_in[7];
  const float* Wcw = (const float*)d_in[8];
  const float* Wcb = (const float*)d_in[9];
  const float* Wiw = (const float*)d_in[10];
  const float* Wib = (const float*)d_in[11];
  const float* Wfw = (const float*)d_in[12];
  const float* Wfb = (const float*)d_in[13];
  const float* bc = (const float*)d_in[14];
  const float* bi = (const float*)d_in[15];
  const float* bf = (const float*)d_in[16];

  char* ws = (char*)d_ws;
  unsigned short* Ahi = (unsigned short*)(ws + OFF_AHI);
  unsigned short* Alo = (unsigned short*)(ws + OFF_ALO);
  unsigned short* Bhi = (unsigned short*)(ws + OFF_BHI);
  unsigned short* Blo = (unsigned short*)(ws + OFF_BLO);
  float* partials = (float*)(ws + OFF_PART);
  float* scores = (float*)(ws + OFF_SCORE);
  float* zbuf = (float*)(ws + OFF_Z);
  float* tmean = (float*)(ws + OFF_TMEAN);
  float* tg = (float*)(ws + OFF_TG);
  float* ybuf = (float*)(ws + OFF_Y);
  float* base1 = (float*)(ws + OFF_BASE1);
  float* cA = (float*)(ws + OFF_CA);
  float* cB = (float*)(ws + OFF_CB);
  float* sgA = (float*)(ws + OFF_SGA);
  float* sgB = (float*)(ws + OFF_SGB);
  float* svec = (float*)(ws + OFF_S);
  float* uvec = (float*)(ws + OFF_U);
  float* wtil = (float*)(ws + OFF_WT);
  float* scal = (float*)(ws + OFF_SCAL);
  float* conf = (float*)(ws + OFF_CONF);
  int* sel_li = (int*)(ws + OFF_SELLI);
  int* sel_idx = (int*)(ws + OFF_SELIX);

  // prep: means + text_global LN
  k_text_mean<<<4, 256, 0, stream>>>((const float4*)tf, (float4*)tmean);
  k_ln_vec<<<1, 256, 0, stream>>>(tmean, tg);
  k_y_mean<<<96, 256, 0, stream>>>((const float4*)proj, (float4*)ybuf);
  k_base1<<<1024, 256, 0, stream>>>(W1w, W1b, ybuf, tg, base1);
  k_init<<<16, 256, 0, stream>>>(cA, sgA);

  // DSU recurrence (only need contexts[22] => 23 iterations)
  float* cbuf[2] = {cA, cB};
  float* sgbuf[2] = {sgA, sgB};
  for (int l = 0; l < 23; ++l) {
    int pi = l & 1;
    k_dsu_A<<<1024, 256, 0, stream>>>((const float4*)W1w, (const float4*)sgbuf[pi],
                                      base1 + (size_t)l * RED, svec);
    k_dsu_B<<<4096, 192, 0, stream>>>((const float4*)Wcw, (const float4*)Wiw, (const float4*)Wfw,
                                      Wcb, Wib, Wfb, bc, bi, bf,
                                      (const float4*)svec, cbuf[pi], cbuf[1 - pi], sgbuf[1 - pi]);
  }
  // c_final = cbuf[1] (after l=22)
  k_qvec<<<4096, 256, 0, stream>>>((const float4*)Wq, (const float4*)cbuf[1], uvec);
  k_qln<<<1, 256, 0, stream>>>(uvec, ln_w, ln_b, wtil, scal);

  // split-bf16 conversions
  k_split<<<55296, 256, 0, stream>>>((const float4*)proj, (ushort4*)Ahi, (ushort4*)Alo);
  k_split<<<16384, 256, 0, stream>>>((const float4*)Wk, (ushort4*)Bhi, (ushort4*)Blo);

  // main GEMM with fused per-row stats — n-tiles fastest for A/B L3 reuse
  k_gemm<<<dim3(32, 108), 256, 0, stream>>>(Ahi, Alo, Bhi, Blo, wtil, partials);

  // scores -> z -> select -> gather
  k_scorefin<<<54, 256, 0, stream>>>(partials, scal, scores);
  k_zscore<<<24, 256, 0, stream>>>(scores, zbuf, conf);
  k_select<<<1, 64, 0, stream>>>(zbuf, conf, sel_li, sel_idx);
  k_gather<<<64, 256, 0, stream>>>((const float4*)proj, sel_li, sel_idx, (float4*)d_out);
}